// Round 6
// baseline (577.415 us; speedup 1.0000x reference)
//
#include <hip/hip_runtime.h>
#include <hip/hip_bf16.h>
#include <stdint.h>

#define M_DIM 8192
#define N_DIM 4096
#define K_DIM 4096
#define FP8MAX 448.0f
#define CANARY 0x5CA1AB1Eu

typedef float floatx4 __attribute__((ext_vector_type(4)));
typedef short short8 __attribute__((ext_vector_type(8)));

// f32 -> bf16 bits, RNE. Exact for fp8-grid values.
__device__ __forceinline__ unsigned int f2bfbits(float f) {
    union { float f; unsigned int u; } v; v.f = f;
    return (v.u + 0x7fffu + ((v.u >> 16) & 1u)) >> 16;
}

// ---------- kernel 1 (runs FIRST): in-place W fp32 -> bf16 (exact on fp8 grid) ----------
// Thread owns one 256B region (64 f32). Reads ALL 256B into regs, writes 128B bf16 to front.
// Back 128B of every region becomes free scratch (GEMM never reads it).
__global__ __launch_bounds__(256) void quant_w_kernel(unsigned char* wbuf) {
    const size_t t = (size_t)blockIdx.x * 256 + threadIdx.x;   // 262144 regions exactly
    uint4* p = (uint4*)(wbuf + t * 256);
    uint4 r[16];
    #pragma unroll
    for (int i = 0; i < 16; ++i) r[i] = p[i];
    const float* f = (const float*)r;
    unsigned int o[32];
    #pragma unroll
    for (int i = 0; i < 16; ++i) {
        unsigned int b0 = f2bfbits(f[4 * i + 0]);
        unsigned int b1 = f2bfbits(f[4 * i + 1]);
        unsigned int b2 = f2bfbits(f[4 * i + 2]);
        unsigned int b3 = f2bfbits(f[4 * i + 3]);
        ((uint2*)o)[i] = make_uint2(b0 | (b1 << 16), b2 | (b3 << 16));
    }
    uint4* q = (uint4*)(wbuf + t * 256);
    #pragma unroll
    for (int i = 0; i < 8; ++i) q[i] = ((uint4*)o)[i];
}

// ---------- kernel 2: in-place quantize x: fp32 -> e4m3(RNE,sat) -> bf16, spread layout ----------
// Thread owns one 256B region (64 fp32). Reads all 256B, absmax on ORIGINAL values, writes
// 128B bf16 (e4m3 roundtrip) to front. Partial max for block b stashed in W region (b+1)'s
// back half (byte (b+1)*256+128).
__global__ __launch_bounds__(256) void quant_x_kernel(unsigned char* xbuf, unsigned char* wbuf) {
    const size_t t = (size_t)blockIdx.x * 256 + threadIdx.x;   // 524288 regions exactly
    uint4* p = (uint4*)(xbuf + t * 256);
    uint4 r[16];
    #pragma unroll
    for (int i = 0; i < 16; ++i) r[i] = p[i];
    const float* f = (const float*)r;
    float vmax = 0.f;
    unsigned int o[32];
    #pragma unroll
    for (int i = 0; i < 16; ++i) {
        float a = f[4 * i + 0], b = f[4 * i + 1], c = f[4 * i + 2], d = f[4 * i + 3];
        vmax = fmaxf(vmax, fmaxf(fmaxf(fabsf(a), fabsf(b)), fmaxf(fabsf(c), fabsf(d))));
        int p8 = __builtin_amdgcn_cvt_pk_fp8_f32(a, b, 0, false);    // e4m3 RNE saturating
        p8 = __builtin_amdgcn_cvt_pk_fp8_f32(c, d, p8, true);
        float qa = __builtin_amdgcn_cvt_f32_fp8(p8, 0);
        float qb = __builtin_amdgcn_cvt_f32_fp8(p8, 1);
        float qc = __builtin_amdgcn_cvt_f32_fp8(p8, 2);
        float qd = __builtin_amdgcn_cvt_f32_fp8(p8, 3);
        ((uint2*)o)[i] = make_uint2(f2bfbits(qa) | (f2bfbits(qb) << 16),
                                    f2bfbits(qc) | (f2bfbits(qd) << 16));
    }
    uint4* q = (uint4*)(xbuf + t * 256);
    #pragma unroll
    for (int i = 0; i < 8; ++i) q[i] = ((uint4*)o)[i];
    // wave then block max
    #pragma unroll
    for (int off = 32; off >= 1; off >>= 1)
        vmax = fmaxf(vmax, __shfl_xor(vmax, off, 64));
    __shared__ float smax[4];
    if ((threadIdx.x & 63) == 0) smax[threadIdx.x >> 6] = vmax;
    __syncthreads();
    if (threadIdx.x == 0)
        *(float*)(wbuf + ((size_t)blockIdx.x + 1) * 256 + 128) =
            fmaxf(fmaxf(smax[0], smax[1]), fmaxf(smax[2], smax[3]));
}

// ---------- kernel 3: scale = max(absmax,1e-12)/448 * wscale -> W region 0 back half ----------
__global__ __launch_bounds__(256) void scale_kernel(unsigned char* wbuf, const float* wscale) {
    float vmax = 0.f;
    for (int i = threadIdx.x; i < 2048; i += 256)
        vmax = fmaxf(vmax, *(const float*)(wbuf + ((size_t)i + 1) * 256 + 128));
    #pragma unroll
    for (int off = 32; off >= 1; off >>= 1)
        vmax = fmaxf(vmax, __shfl_xor(vmax, off, 64));
    __shared__ float smax[4];
    if ((threadIdx.x & 63) == 0) smax[threadIdx.x >> 6] = vmax;
    __syncthreads();
    if (threadIdx.x == 0) {
        float m = fmaxf(fmaxf(smax[0], smax[1]), fmaxf(smax[2], smax[3]));
        *(float*)(wbuf + 128) = (fmaxf(m, 1e-12f) / FP8MAX) * wscale[0];
        *(unsigned int*)(wbuf + 132) = CANARY;
    }
}

// ---------- kernel 4: bf16 GEMM, 128x128 tile, BK=64, 4 waves x 4x4 16x16x32 MFMAs ----------
// A and B both spread bf16: row r, k-tile kt at byte r*16384 + kt*256, front 128B valid
// (64 bf16 = one k-tile). Scale at Bq+128, canary at Bq+132 (W region 0 back half).
// LDS rows padded to 72 shorts -> at most 2-way bank aliasing on b128 frag reads (free).
// Output fp32 row-major [8192][4096]; bias fp32.
__global__ __launch_bounds__(256, 2) void gemm_bf16_kernel(
    const unsigned char* __restrict__ Aq,
    const unsigned char* __restrict__ Bq,
    const float* __restrict__ bias,
    float* __restrict__ out) {
    __shared__ __align__(16) short lds[2 * 128 * 72];   // A @0, B @9216 (shorts)
    const int tid = threadIdx.x;
    const int l = tid & 63, wv = tid >> 6, wm = wv >> 1, wn = wv & 1;
    const int bm = blockIdx.y, bn = blockIdx.x;
    const int r = tid >> 1, kq = (tid & 1) * 64;        // staging: row r, 64B sub-chunk kq

    const float scl = *(const float*)(Bq + 128);
    const unsigned int canary = *(const unsigned int*)(Bq + 132);

    const unsigned char* gA = Aq + (size_t)(bm * 128 + r) * 16384 + kq;
    const unsigned char* gB = Bq + (size_t)(bn * 128 + r) * 16384 + kq;
    short* sA = lds + r * 72 + kq / 2;
    short* sB = lds + 9216 + r * 72 + kq / 2;

    int aOff[4][2], bOff[4][2];
    #pragma unroll
    for (int i = 0; i < 4; ++i) {
        #pragma unroll
        for (int s = 0; s < 2; ++s) {
            int rowa = wm * 64 + i * 16 + (l & 15);
            aOff[i][s] = rowa * 72 + s * 32 + (l >> 4) * 8;
            int rowb = wn * 64 + i * 16 + (l & 15);
            bOff[i][s] = 9216 + rowb * 72 + s * 32 + (l >> 4) * 8;
        }
    }

    floatx4 acc[4][4];
    #pragma unroll
    for (int i = 0; i < 4; ++i)
        #pragma unroll
        for (int j = 0; j < 4; ++j)
            acc[i][j] = (floatx4)0.f;

    for (int kt = 0; kt < K_DIM / 64; ++kt) {
        uint4 a0 = *(const uint4*)(gA);
        uint4 a1 = *(const uint4*)(gA + 16);
        uint4 a2 = *(const uint4*)(gA + 32);
        uint4 a3 = *(const uint4*)(gA + 48);
        uint4 b0 = *(const uint4*)(gB);
        uint4 b1 = *(const uint4*)(gB + 16);
        uint4 b2 = *(const uint4*)(gB + 32);
        uint4 b3 = *(const uint4*)(gB + 48);
        gA += 256;   // next 256B region (same row, next k-tile)
        gB += 256;
        __syncthreads();           // prior iteration's frag reads done
        *(uint4*)(sA +  0) = a0;  *(uint4*)(sA +  8) = a1;
        *(uint4*)(sA + 16) = a2;  *(uint4*)(sA + 24) = a3;
        *(uint4*)(sB +  0) = b0;  *(uint4*)(sB +  8) = b1;
        *(uint4*)(sB + 16) = b2;  *(uint4*)(sB + 24) = b3;
        __syncthreads();           // tiles visible

        short8 af[4][2], bf[4][2];
        #pragma unroll
        for (int i = 0; i < 4; ++i) {
            af[i][0] = *(const short8*)(lds + aOff[i][0]);
            af[i][1] = *(const short8*)(lds + aOff[i][1]);
            bf[i][0] = *(const short8*)(lds + bOff[i][0]);
            bf[i][1] = *(const short8*)(lds + bOff[i][1]);
        }
        #pragma unroll
        for (int s = 0; s < 2; ++s)
            #pragma unroll
            for (int i = 0; i < 4; ++i)
                #pragma unroll
                for (int j = 0; j < 4; ++j)
                    acc[i][j] = __builtin_amdgcn_mfma_f32_16x16x32_bf16(
                        af[i][s], bf[j][s], acc[i][j], 0, 0, 0);
    }

    // epilogue + discriminator. Expected scl ~ 3.1e-6.
    //   222 = canary missing   1000 = scl NaN or >1e-1   777 = scl in (1e-4,1e-1]
    //   333 = scl < 1e-8       111 = bias NaN            555 = acc NaN
    float marker = 0.f;
    if (canary != CANARY) marker = 222.f;
    else if (scl != scl || fabsf(scl) > 1e-1f) marker = 1000.f;
    else if (fabsf(scl) > 1e-4f) marker = 777.f;
    else if (fabsf(scl) < 1e-8f) marker = 333.f;

    float bj[4];
    #pragma unroll
    for (int j = 0; j < 4; ++j) {
        int col = bn * 128 + wn * 64 + j * 16 + (l & 15);
        bj[j] = bias[col];
    }
    #pragma unroll
    for (int i = 0; i < 4; ++i) {
        #pragma unroll
        for (int rr = 0; rr < 4; ++rr) {
            int row = bm * 128 + wm * 64 + i * 16 + (l >> 4) * 4 + rr;
            float* orow = out + (size_t)row * N_DIM;
            #pragma unroll
            for (int j = 0; j < 4; ++j) {
                int col = bn * 128 + wn * 64 + j * 16 + (l & 15);
                float v = acc[i][j][rr] * scl + bj[j];
                if (marker != 0.f) v = marker;
                else if (bj[j] != bj[j]) v = 111.f;
                else if (v != v) v = 555.f;
                orow[col] = v;
            }
        }
    }
}

extern "C" void kernel_launch(void* const* d_in, const int* in_sizes, int n_in,
                              void* d_out, int out_size, void* d_ws, size_t ws_size,
                              hipStream_t stream) {
    unsigned char* x = (unsigned char*)d_in[0];   // fp32 [8192][4096] (fp16 promoted) — in-place
    unsigned char* w = (unsigned char*)d_in[1];   // fp32 exact-fp8 [4096][4096] — in-place
    const float* wscale = (const float*)d_in[2];  // fp32 [1]
    const float* bias = (const float*)d_in[3];    // fp32 [4096] (fp16 promoted)
    float* out = (float*)d_out;                   // fp32 [8192][4096] (fp16-output promoted)
    (void)d_ws; (void)ws_size;                    // d_ws not used (size unknown)

    // Order matters: quant_w reads pristine full W regions BEFORE quant_x stashes
    // partial maxima into W region back halves.
    quant_w_kernel<<<1024, 256, 0, stream>>>(w);
    quant_x_kernel<<<2048, 256, 0, stream>>>(x, w);
    scale_kernel<<<1, 256, 0, stream>>>(w, wscale);
    gemm_bf16_kernel<<<dim3(N_DIM / 128, M_DIM / 128), 256, 0, stream>>>(
        x, w, bias, out);
}

// Round 7
// 556.474 us; speedup vs baseline: 1.0376x; 1.0376x over previous
//
#include <hip/hip_runtime.h>
#include <hip/hip_bf16.h>
#include <stdint.h>

#define M_DIM 8192
#define N_DIM 4096
#define K_DIM 4096
#define FP8MAX 448.0f
#define CANARY 0x5CA1AB1Eu

typedef float floatx4 __attribute__((ext_vector_type(4)));
typedef short short8 __attribute__((ext_vector_type(8)));

// f32 -> bf16 bits, RNE. Exact for fp8-grid values.
__device__ __forceinline__ unsigned int f2bfbits(float f) {
    union { float f; unsigned int u; } v; v.f = f;
    return (v.u + 0x7fffu + ((v.u >> 16) & 1u)) >> 16;
}

// fp32x4 -> e4m3(RNE,sat) -> bf16x4 packed into uint2
__device__ __forceinline__ uint2 quant4(float a, float b, float c, float d) {
    int p8 = __builtin_amdgcn_cvt_pk_fp8_f32(a, b, 0, false);
    p8 = __builtin_amdgcn_cvt_pk_fp8_f32(c, d, p8, true);
    float qa = __builtin_amdgcn_cvt_f32_fp8(p8, 0);
    float qb = __builtin_amdgcn_cvt_f32_fp8(p8, 1);
    float qc = __builtin_amdgcn_cvt_f32_fp8(p8, 2);
    float qd = __builtin_amdgcn_cvt_f32_fp8(p8, 3);
    return make_uint2(f2bfbits(qa) | (f2bfbits(qb) << 16),
                      f2bfbits(qc) | (f2bfbits(qd) << 16));
}

// ================= WS (compact) path: fully coalesced prepass =================

// x fp32 -> e4m3 roundtrip -> compact bf16 in ws; block absmax -> partials[b]
__global__ __launch_bounds__(256) void quant_x_ws(const uint4* __restrict__ x,
                                                  uint2* __restrict__ xq,
                                                  float* __restrict__ partials) {
    const int tid = blockIdx.x * 256 + threadIdx.x;
    float vmax = 0.f;
    for (int c = tid; c < (M_DIM * K_DIM) / 4; c += 2048 * 256) {
        uint4 v = x[c];
        float a = __uint_as_float(v.x), b = __uint_as_float(v.y);
        float cc = __uint_as_float(v.z), d = __uint_as_float(v.w);
        vmax = fmaxf(vmax, fmaxf(fmaxf(fabsf(a), fabsf(b)), fmaxf(fabsf(cc), fabsf(d))));
        xq[c] = quant4(a, b, cc, d);
    }
    #pragma unroll
    for (int off = 32; off >= 1; off >>= 1)
        vmax = fmaxf(vmax, __shfl_xor(vmax, off, 64));
    __shared__ float smax[4];
    if ((threadIdx.x & 63) == 0) smax[threadIdx.x >> 6] = vmax;
    __syncthreads();
    if (threadIdx.x == 0)
        partials[blockIdx.x] = fmaxf(fmaxf(smax[0], smax[1]), fmaxf(smax[2], smax[3]));
}

// w fp32 (exact fp8 values) -> compact bf16 in ws (bf16 cast exact on fp8 grid)
__global__ __launch_bounds__(256) void quant_w_ws(const uint4* __restrict__ w,
                                                  uint2* __restrict__ wq) {
    const int tid = blockIdx.x * 256 + threadIdx.x;
    for (int c = tid; c < (N_DIM * K_DIM) / 4; c += 1024 * 256) {
        uint4 v = w[c];
        float a = __uint_as_float(v.x), b = __uint_as_float(v.y);
        float cc = __uint_as_float(v.z), d = __uint_as_float(v.w);
        unsigned int b0 = f2bfbits(a), b1 = f2bfbits(b), b2 = f2bfbits(cc), b3 = f2bfbits(d);
        wq[c] = make_uint2(b0 | (b1 << 16), b2 | (b3 << 16));
    }
}

// reduce 2048 contiguous partials -> scale (+canary) at scb
__global__ __launch_bounds__(256) void scale_ws(const float* __restrict__ partials,
                                                const float* __restrict__ wscale,
                                                float* __restrict__ scb) {
    float vmax = 0.f;
    for (int i = threadIdx.x; i < 2048; i += 256) vmax = fmaxf(vmax, partials[i]);
    #pragma unroll
    for (int off = 32; off >= 1; off >>= 1)
        vmax = fmaxf(vmax, __shfl_xor(vmax, off, 64));
    __shared__ float smax[4];
    if ((threadIdx.x & 63) == 0) smax[threadIdx.x >> 6] = vmax;
    __syncthreads();
    if (threadIdx.x == 0) {
        float m = fmaxf(fmaxf(smax[0], smax[1]), fmaxf(smax[2], smax[3]));
        scb[0] = (fmaxf(m, 1e-12f) / FP8MAX) * wscale[0];
        ((unsigned int*)scb)[1] = CANARY;
    }
}

// ================= Fallback (in-place spread) path: round-6 verbatim =================

__global__ __launch_bounds__(256) void quant_w_kernel(unsigned char* wbuf) {
    const size_t t = (size_t)blockIdx.x * 256 + threadIdx.x;   // 262144 regions
    uint4* p = (uint4*)(wbuf + t * 256);
    uint4 r[16];
    #pragma unroll
    for (int i = 0; i < 16; ++i) r[i] = p[i];
    const float* f = (const float*)r;
    unsigned int o[32];
    #pragma unroll
    for (int i = 0; i < 16; ++i) {
        unsigned int b0 = f2bfbits(f[4 * i + 0]);
        unsigned int b1 = f2bfbits(f[4 * i + 1]);
        unsigned int b2 = f2bfbits(f[4 * i + 2]);
        unsigned int b3 = f2bfbits(f[4 * i + 3]);
        ((uint2*)o)[i] = make_uint2(b0 | (b1 << 16), b2 | (b3 << 16));
    }
    uint4* q = (uint4*)(wbuf + t * 256);
    #pragma unroll
    for (int i = 0; i < 8; ++i) q[i] = ((uint4*)o)[i];
}

__global__ __launch_bounds__(256) void quant_x_kernel(unsigned char* xbuf, unsigned char* wbuf) {
    const size_t t = (size_t)blockIdx.x * 256 + threadIdx.x;   // 524288 regions
    uint4* p = (uint4*)(xbuf + t * 256);
    uint4 r[16];
    #pragma unroll
    for (int i = 0; i < 16; ++i) r[i] = p[i];
    const float* f = (const float*)r;
    float vmax = 0.f;
    unsigned int o[32];
    #pragma unroll
    for (int i = 0; i < 16; ++i) {
        float a = f[4 * i + 0], b = f[4 * i + 1], c = f[4 * i + 2], d = f[4 * i + 3];
        vmax = fmaxf(vmax, fmaxf(fmaxf(fabsf(a), fabsf(b)), fmaxf(fabsf(c), fabsf(d))));
        ((uint2*)o)[i] = quant4(a, b, c, d);
    }
    uint4* q = (uint4*)(xbuf + t * 256);
    #pragma unroll
    for (int i = 0; i < 8; ++i) q[i] = ((uint4*)o)[i];
    #pragma unroll
    for (int off = 32; off >= 1; off >>= 1)
        vmax = fmaxf(vmax, __shfl_xor(vmax, off, 64));
    __shared__ float smax[4];
    if ((threadIdx.x & 63) == 0) smax[threadIdx.x >> 6] = vmax;
    __syncthreads();
    if (threadIdx.x == 0)
        *(float*)(wbuf + ((size_t)blockIdx.x + 1) * 256 + 128) =
            fmaxf(fmaxf(smax[0], smax[1]), fmaxf(smax[2], smax[3]));
}

__global__ __launch_bounds__(256) void scale_kernel(unsigned char* wbuf, const float* wscale) {
    float vmax = 0.f;
    for (int i = threadIdx.x; i < 2048; i += 256)
        vmax = fmaxf(vmax, *(const float*)(wbuf + ((size_t)i + 1) * 256 + 128));
    #pragma unroll
    for (int off = 32; off >= 1; off >>= 1)
        vmax = fmaxf(vmax, __shfl_xor(vmax, off, 64));
    __shared__ float smax[4];
    if ((threadIdx.x & 63) == 0) smax[threadIdx.x >> 6] = vmax;
    __syncthreads();
    if (threadIdx.x == 0) {
        float m = fmaxf(fmaxf(smax[0], smax[1]), fmaxf(smax[2], smax[3]));
        *(float*)(wbuf + 128) = (fmaxf(m, 1e-12f) / FP8MAX) * wscale[0];
        *(unsigned int*)(wbuf + 132) = CANARY;
    }
}

// ========== GEMM: round-6 structure, strides parametrized (rs=row bytes, kt=k-tile bytes) ==========
// Valid data: row r, k-tile kt at byte r*rs + kt*ktb, 128 contiguous bytes (64 bf16).
// Compact: rs=8192, ktb=128. Spread: rs=16384, ktb=256. scb -> {float scale, uint canary}.
__global__ __launch_bounds__(256, 2) void gemm_bf16_kernel(
    const unsigned char* __restrict__ Aq,
    const unsigned char* __restrict__ Bq,
    int rs, int ktb,
    const unsigned char* __restrict__ scb,
    const float* __restrict__ bias,
    float* __restrict__ out) {
    __shared__ __align__(16) short lds[2 * 128 * 72];   // A @0, B @9216 (shorts)
    const int tid = threadIdx.x;
    const int l = tid & 63, wv = tid >> 6, wm = wv >> 1, wn = wv & 1;
    const int bm = blockIdx.y, bn = blockIdx.x;
    const int r = tid >> 1, kq = (tid & 1) * 64;        // staging: row r, 64B sub-chunk kq

    const float scl = *(const float*)scb;
    const unsigned int canary = *(const unsigned int*)(scb + 4);

    const unsigned char* gA = Aq + (size_t)(bm * 128 + r) * rs + kq;
    const unsigned char* gB = Bq + (size_t)(bn * 128 + r) * rs + kq;
    short* sA = lds + r * 72 + kq / 2;
    short* sB = lds + 9216 + r * 72 + kq / 2;

    int aOff[4][2], bOff[4][2];
    #pragma unroll
    for (int i = 0; i < 4; ++i) {
        #pragma unroll
        for (int s = 0; s < 2; ++s) {
            int rowa = wm * 64 + i * 16 + (l & 15);
            aOff[i][s] = rowa * 72 + s * 32 + (l >> 4) * 8;
            int rowb = wn * 64 + i * 16 + (l & 15);
            bOff[i][s] = 9216 + rowb * 72 + s * 32 + (l >> 4) * 8;
        }
    }

    floatx4 acc[4][4];
    #pragma unroll
    for (int i = 0; i < 4; ++i)
        #pragma unroll
        for (int j = 0; j < 4; ++j)
            acc[i][j] = (floatx4)0.f;

    for (int kt = 0; kt < K_DIM / 64; ++kt) {
        uint4 a0 = *(const uint4*)(gA);
        uint4 a1 = *(const uint4*)(gA + 16);
        uint4 a2 = *(const uint4*)(gA + 32);
        uint4 a3 = *(const uint4*)(gA + 48);
        uint4 b0 = *(const uint4*)(gB);
        uint4 b1 = *(const uint4*)(gB + 16);
        uint4 b2 = *(const uint4*)(gB + 32);
        uint4 b3 = *(const uint4*)(gB + 48);
        gA += ktb;
        gB += ktb;
        __syncthreads();           // prior iteration's frag reads done
        *(uint4*)(sA +  0) = a0;  *(uint4*)(sA +  8) = a1;
        *(uint4*)(sA + 16) = a2;  *(uint4*)(sA + 24) = a3;
        *(uint4*)(sB +  0) = b0;  *(uint4*)(sB +  8) = b1;
        *(uint4*)(sB + 16) = b2;  *(uint4*)(sB + 24) = b3;
        __syncthreads();           // tiles visible

        short8 af[4][2], bf[4][2];
        #pragma unroll
        for (int i = 0; i < 4; ++i) {
            af[i][0] = *(const short8*)(lds + aOff[i][0]);
            af[i][1] = *(const short8*)(lds + aOff[i][1]);
            bf[i][0] = *(const short8*)(lds + bOff[i][0]);
            bf[i][1] = *(const short8*)(lds + bOff[i][1]);
        }
        #pragma unroll
        for (int s = 0; s < 2; ++s)
            #pragma unroll
            for (int i = 0; i < 4; ++i)
                #pragma unroll
                for (int j = 0; j < 4; ++j)
                    acc[i][j] = __builtin_amdgcn_mfma_f32_16x16x32_bf16(
                        af[i][s], bf[j][s], acc[i][j], 0, 0, 0);
    }

    // epilogue + discriminator. Expected scl ~ 3.1e-6.
    float marker = 0.f;
    if (canary != CANARY) marker = 222.f;
    else if (scl != scl || fabsf(scl) > 1e-1f) marker = 1000.f;
    else if (fabsf(scl) > 1e-4f) marker = 777.f;
    else if (fabsf(scl) < 1e-8f) marker = 333.f;

    float bj[4];
    #pragma unroll
    for (int j = 0; j < 4; ++j) {
        int col = bn * 128 + wn * 64 + j * 16 + (l & 15);
        bj[j] = bias[col];
    }
    #pragma unroll
    for (int i = 0; i < 4; ++i) {
        #pragma unroll
        for (int rr = 0; rr < 4; ++rr) {
            int row = bm * 128 + wm * 64 + i * 16 + (l >> 4) * 4 + rr;
            float* orow = out + (size_t)row * N_DIM;
            #pragma unroll
            for (int j = 0; j < 4; ++j) {
                int col = bn * 128 + wn * 64 + j * 16 + (l & 15);
                float v = acc[i][j][rr] * scl + bj[j];
                if (marker != 0.f) v = marker;
                else if (bj[j] != bj[j]) v = 111.f;
                else if (v != v) v = 555.f;
                orow[col] = v;
            }
        }
    }
}

extern "C" void kernel_launch(void* const* d_in, const int* in_sizes, int n_in,
                              void* d_out, int out_size, void* d_ws, size_t ws_size,
                              hipStream_t stream) {
    unsigned char* x = (unsigned char*)d_in[0];   // fp32 [8192][4096] (fp16 promoted)
    unsigned char* w = (unsigned char*)d_in[1];   // fp32 exact-fp8 [4096][4096]
    const float* wscale = (const float*)d_in[2];  // fp32 [1]
    const float* bias = (const float*)d_in[3];    // fp32 [4096] (fp16 promoted)
    float* out = (float*)d_out;                   // fp32 [8192][4096]

    const size_t XQ = (size_t)M_DIM * K_DIM * 2;  // 64MB compact bf16 x
    const size_t WQ = (size_t)N_DIM * K_DIM * 2;  // 32MB compact bf16 w
    unsigned char* ws = (unsigned char*)d_ws;

    if (ws_size >= XQ + WQ + 2048 * 4 + 64) {
        // ---- compact path: coalesced prepass into ws, dense GEMM ----
        unsigned char* xq = ws;
        unsigned char* wq = ws + XQ;
        float* partials = (float*)(ws + XQ + WQ);
        unsigned char* scb = ws + XQ + WQ + 8192;
        quant_w_ws<<<1024, 256, 0, stream>>>((const uint4*)w, (uint2*)wq);
        quant_x_ws<<<2048, 256, 0, stream>>>((const uint4*)x, (uint2*)xq, partials);
        scale_ws<<<1, 256, 0, stream>>>(partials, wscale, (float*)scb);
        gemm_bf16_kernel<<<dim3(N_DIM / 128, M_DIM / 128), 256, 0, stream>>>(
            xq, wq, 8192, 128, scb, bias, out);
    } else {
        // ---- fallback: round-6 in-place spread path (proven) ----
        quant_w_kernel<<<1024, 256, 0, stream>>>(w);
        quant_x_kernel<<<2048, 256, 0, stream>>>(x, w);
        scale_kernel<<<1, 256, 0, stream>>>(w, wscale);
        gemm_bf16_kernel<<<dim3(N_DIM / 128, M_DIM / 128), 256, 0, stream>>>(
            x, w, 16384, 256, w + 128, bias, out);
    }
}